// Round 7
// baseline (4049.151 us; speedup 1.0000x reference)
//
#include <hip/hip_runtime.h>
#include <hip/hip_bf16.h>

// DecoderRNN: B=32,P=196,E=H=A=512,V=32000,T=50
// v8: 32-block persistent scan (one block per batch).  Key insight: every scan
//     stage except the gates GEMM is per-batch independent -> block b computes
//     finalize/dec_att/scores/softmax/awe for its own batch IN-BLOCK (no
//     replication, no partial exchanges).  Only 2 sync points/step, and the
//     barrier has 32 arrivals (~1-2us) instead of 256 (~10us, rounds 2-5).
//     Phase2: same 32 blocks do the gates GEMM by j-slice (64 j each, M=32
//     MFMA, full-K accumulate -> FINAL gates, no gpart partial-sum).
//     L2/XCD: 4 batches x (encbf+F2hi 400K) + W_dec f32 1MB + 4 Wcat2 slices
//     1MB ~= 3.2MB < 4MB resident.  dec_att uses f32 W_dec directly.

typedef __attribute__((ext_vector_type(8))) short short8;
typedef __attribute__((ext_vector_type(4))) float f32x4;
typedef unsigned long long u64;

#define BARSTRIDE 32  // uints between counters (128 B)
#define NBAR 112      // sync points used: 100

__device__ __forceinline__ unsigned short f2bf(float x) {
  __hip_bfloat16 h = __float2bfloat16(x);
  return __builtin_bit_cast(unsigned short, h);
}
__device__ __forceinline__ float bf2f(unsigned short u) {
  unsigned int v = ((unsigned int)u) << 16;
  return __builtin_bit_cast(float, v);
}
__device__ __forceinline__ void gl_lds16(const void* g, void* l) {
  __builtin_amdgcn_global_load_lds(
      (const __attribute__((address_space(1))) unsigned int*)g,
      (__attribute__((address_space(3))) unsigned int*)l, 16, 0, 0);
}
// coherent (agent-scope, cache-bypassing, NO cache-maintenance) accessors
__device__ __forceinline__ u64 cload64(const void* p) {
  return __hip_atomic_load((const u64*)p, __ATOMIC_RELAXED, __HIP_MEMORY_SCOPE_AGENT);
}
__device__ __forceinline__ float2 bc2(u64 v) { return __builtin_bit_cast(float2, v); }
__device__ __forceinline__ void cstore32(void* p, unsigned int v) {
  __hip_atomic_store((unsigned int*)p, v, __ATOMIC_RELAXED, __HIP_MEMORY_SCOPE_AGENT);
}
__device__ __forceinline__ void cstoref(void* p, float v) {
  cstore32(p, __builtin_bit_cast(unsigned int, v));
}
__device__ __forceinline__ float2 ntload2(const float* p) {
  u64 v = __builtin_nontemporal_load((const u64*)p);
  return __builtin_bit_cast(float2, v);
}

// 32-block grid barrier: dedicated counter per sync point; no cache-wide fences.
__device__ __forceinline__ void gbar32(unsigned int* ctr) {
  asm volatile("s_waitcnt vmcnt(0)" ::: "memory");
  __syncthreads();
  if (threadIdx.x == 0) {
    __hip_atomic_fetch_add(ctr, 1u, __ATOMIC_RELAXED, __HIP_MEMORY_SCOPE_AGENT);
    while (__hip_atomic_load(ctr, __ATOMIC_RELAXED, __HIP_MEMORY_SCOPE_AGENT) < 32u)
      __builtin_amdgcn_s_sleep(1);
  }
  asm volatile("" ::: "memory");
  __syncthreads();
}

__global__ void k_zero(unsigned int* __restrict__ p, int n) {
  int i = blockIdx.x * blockDim.x + threadIdx.x;
  if (i < n) p[i] = 0;
}

// ---- prep: f32 [rows,512] -> bf16 split [rows,1024] ([0,512)=hi, [512,1024)=lo)
__global__ void k_split(const float* __restrict__ src, unsigned short* __restrict__ dst,
                        int rows, int src_ld) {
  int n = rows * 512;
  for (int i = blockIdx.x * blockDim.x + threadIdx.x; i < n; i += gridDim.x * blockDim.x) {
    int r = i >> 9, c = i & 511;
    float x = src[(size_t)r * src_ld + c];
    unsigned short hi = f2bf(x);
    unsigned short lo = f2bf(x - bf2f(hi));
    dst[(size_t)r * 1024 + c] = hi;
    dst[(size_t)r * 1024 + 512 + c] = lo;
  }
}

// ---- prep: Wcat2 [2048 j][2048]: cols [0,512)=hi(W_ih[j,512+c]) [512,1024)=hi(W_hh[j,c]),
//      [1024,2048) = same but lo.  Matches xh2 layout [awe_hi|h_hi|awe_lo|h_lo].
__global__ void k_wcat2(const float* __restrict__ Wih, const float* __restrict__ Whh,
                        unsigned short* __restrict__ dst) {
  int n = 2048 * 1024;
  for (int i = blockIdx.x * blockDim.x + threadIdx.x; i < n; i += gridDim.x * blockDim.x) {
    int j = i >> 10, c = i & 1023;
    float x = (c < 512) ? Wih[(size_t)j * 1024 + 512 + c] : Whh[(size_t)j * 512 + (c - 512)];
    unsigned short hi = f2bf(x);
    unsigned short lo = f2bf(x - bf2f(hi));
    dst[(size_t)j * 2048 + c] = hi;
    dst[(size_t)j * 2048 + 1024 + c] = lo;
  }
}

// ---- prep: X2 [1600,1024] split-bf16 of emb[captions]; row m = b*50+t
__global__ void k_xgather(const int* __restrict__ captions, const float* __restrict__ emb,
                          unsigned short* __restrict__ X2) {
  int n = 1600 * 512;
  for (int i = blockIdx.x * blockDim.x + threadIdx.x; i < n; i += gridDim.x * blockDim.x) {
    int m = i >> 9, c = i & 511;
    int tok = captions[m];
    float x = emb[(size_t)tok * 512 + c];
    unsigned short hi = f2bf(x);
    unsigned short lo = f2bf(x - bf2f(hi));
    X2[(size_t)m * 1024 + c] = hi;
    X2[(size_t)m * 1024 + 512 + c] = lo;
  }
}

// ---- split-bf16 GEMM: C[m,n] = sum_k A[m,:]·B[n,:] (3-term hi/lo) + bias1[n] + bias2[n]
// A2 [M,1024], B2 [N,1024]. 128x128 tile, m97 pattern.  Output f32 (C) or bf16 (C16).
// Bijective XCD-chunked swizzle, M-fastest decode: same-N-panel tiles co-reside on one XCD.
__global__ void k_gemm(const unsigned short* __restrict__ A2, const unsigned short* __restrict__ B2,
                       float* __restrict__ C, unsigned short* __restrict__ C16,
                       const float* __restrict__ bias1, const float* __restrict__ bias2,
                       int M, int N) {
  __shared__ short As[128 * 32];
  __shared__ short Bs[128 * 32];
  const int tid = threadIdx.x;
  const int lane = tid & 63;
  const int w = tid >> 6, wm = w >> 1, wn = w & 1;

  const int nbx = gridDim.x, nby = gridDim.y;
  const int nwg = nbx * nby;
  const int bidl = blockIdx.y * nbx + blockIdx.x;
  int flat = bidl;
  if (nwg >= 16) {  // bijective chunked XCD swizzle (m204 formula)
    const int q = nwg >> 3, rrem = nwg & 7;
    const int xcd = bidl & 7, idx = bidl >> 3;
    flat = (xcd < rrem) ? xcd * (q + 1) + idx : rrem * (q + 1) + (xcd - rrem) * q + idx;
  }
  const int mb = flat % nby, nb = flat / nby;  // M fastest: same-N tiles contiguous
  const int m0 = mb * 128, n0 = nb * 128;

  f32x4 acc[4][4];
#pragma unroll
  for (int i = 0; i < 4; ++i)
#pragma unroll
    for (int j = 0; j < 4; ++j) acc[i][j] = (f32x4){0.f, 0.f, 0.f, 0.f};

  const int r0 = tid >> 2;
  const int ce = (tid & 3) << 3;
  int am0 = m0 + r0;      if (am0 >= M) am0 = 0;
  int am1 = m0 + 64 + r0; if (am1 >= M) am1 = 0;
  const int bn0 = n0 + r0, bn1 = n0 + 64 + r0;

  for (int ks = 0; ks < 48; ++ks) {
    int t_ = ks >> 4, k = (ks & 15) << 5;
    int acol = (t_ == 2) ? 512 + k : k;
    int bcol = (t_ == 1) ? 512 + k : k;
    __syncthreads();
    gl_lds16(A2 + (size_t)am0 * 1024 + acol + ce, As + tid * 8);
    gl_lds16(A2 + (size_t)am1 * 1024 + acol + ce, As + 2048 + tid * 8);
    gl_lds16(B2 + (size_t)bn0 * 1024 + bcol + ce, Bs + tid * 8);
    gl_lds16(B2 + (size_t)bn1 * 1024 + bcol + ce, Bs + 2048 + tid * 8);
    __syncthreads();
    short8 af[4], bf[4];
#pragma unroll
    for (int mi = 0; mi < 4; ++mi) {
      int row = wm * 64 + mi * 16 + (lane & 15);
      af[mi] = *(const short8*)(As + row * 32 + (lane >> 4) * 8);
    }
#pragma unroll
    for (int ni = 0; ni < 4; ++ni) {
      int row = wn * 64 + ni * 16 + (lane & 15);
      bf[ni] = *(const short8*)(Bs + row * 32 + (lane >> 4) * 8);
    }
#pragma unroll
    for (int mi = 0; mi < 4; ++mi)
#pragma unroll
      for (int ni = 0; ni < 4; ++ni)
        acc[mi][ni] = __builtin_amdgcn_mfma_f32_16x16x32_bf16(af[mi], bf[ni], acc[mi][ni], 0, 0, 0);
  }

  const int mbb = m0 + wm * 64, nbb = n0 + wn * 64;
#pragma unroll
  for (int ni = 0; ni < 4; ++ni) {
    int n = nbb + ni * 16 + (lane & 15);
    float bv = 0.f;
    if (bias1) bv += bias1[n];
    if (bias2) bv += bias2[n];
#pragma unroll
    for (int mi = 0; mi < 4; ++mi)
#pragma unroll
      for (int r = 0; r < 4; ++r) {
        int m = mbb + mi * 16 + (lane >> 4) * 4 + r;
        if (m < M) {
          float v = acc[mi][ni][r] + bv;
          if (C16) C16[(size_t)m * N + n] = f2bf(v);
          else C[(size_t)m * N + n] = v;
        }
      }
  }
}

// ---- persistent scan: 32 blocks (block b = batch b), 512 threads, 2 barriers/step.
// phase1 (per-batch, in-block): finalize LSTM (gates = gates_x + gbuf), dec_att
//   (f32 W_dec), scores (bf16 enc_att), softmax, awe (F2-hi) -> xh2[b] (coherent).
// phase2 (j-slice jbase=b*64): gates MFMA M=32 full-K -> gbuf (final, coherent).
__global__ void __launch_bounds__(512, 1) k_scan32(
    const float* __restrict__ gates_x, unsigned short* __restrict__ H2,
    unsigned short* xh2, const float* __restrict__ Wdec,
    const float* __restrict__ b_dec, const unsigned short* __restrict__ encbf,
    const float* __restrict__ Wfull, const unsigned short* __restrict__ F2,
    const unsigned short* __restrict__ Wcat2, float* gbuf, unsigned int* bar) {
  const int b = blockIdx.x;
  const int tid = threadIdx.x;

  __shared__ short AS[32][1032];  // 66 KB: phase2 A (xh2 hi, then lo); phase1 aliases
  __shared__ short BS[16 * 2048]; // 64 KB: phase2 B (16 k-step tiles of Wcat2)
  float* h_s   = (float*)&AS[0][0];
  float* dec_s = h_s + 512;
  float* wf_s  = dec_s + 512;
  float* sm    = wf_s + 512;
  float* tmp   = sm + 512;
  float* awe_s = tmp + 512;       // 6*512*4 = 12 KB, fits inside AS

  float c0 = 0.f, c1 = 0.f;       // c-state for u=2*tid, 2*tid+1 (tid<256)

  for (int tau = 0; tau <= 50; ++tau) {
    // ======== phase1a: finalize h_tau ========
    if (tid < 256) {
      const int u0 = tid << 1;
      if (tau > 0) {
        const float* gx = gates_x + (size_t)(b * 50 + tau - 1) * 2048;
        const float* gb = gbuf + (size_t)b * 2048;
        float2 vi = ntload2(gx + u0);
        float2 vf = ntload2(gx + 512 + u0);
        float2 vg = ntload2(gx + 1024 + u0);
        float2 vo = ntload2(gx + 1536 + u0);
        float2 ai = bc2(cload64(gb + u0));
        float2 af = bc2(cload64(gb + 512 + u0));
        float2 ag = bc2(cload64(gb + 1024 + u0));
        float2 ao = bc2(cload64(gb + 1536 + u0));
        float gi0 = vi.x + ai.x, gi1 = vi.y + ai.y;
        float gf0 = vf.x + af.x, gf1 = vf.y + af.y;
        float gg0 = vg.x + ag.x, gg1 = vg.y + ag.y;
        float go0 = vo.x + ao.x, go1 = vo.y + ao.y;
        float si0 = 1.f / (1.f + expf(-gi0)), si1 = 1.f / (1.f + expf(-gi1));
        float sf0 = 1.f / (1.f + expf(-gf0)), sf1 = 1.f / (1.f + expf(-gf1));
        float so0 = 1.f / (1.f + expf(-go0)), so1 = 1.f / (1.f + expf(-go1));
        float cn0 = sf0 * c0 + si0 * tanhf(gg0);
        float cn1 = sf1 * c1 + si1 * tanhf(gg1);
        float hn0 = so0 * tanhf(cn0), hn1 = so1 * tanhf(cn1);
        c0 = cn0; c1 = cn1;
        h_s[u0] = hn0; h_s[u0 + 1] = hn1;
        unsigned short h0hi = f2bf(hn0), h1hi = f2bf(hn1);
        unsigned short h0lo = f2bf(hn0 - bf2f(h0hi)), h1lo = f2bf(hn1 - bf2f(h1hi));
        unsigned int phi = (unsigned int)h0hi | ((unsigned int)h1hi << 16);
        unsigned int plo = (unsigned int)h0lo | ((unsigned int)h1lo << 16);
        const size_t hrow = (size_t)(b * 50 + tau - 1) * 1024;
        __builtin_nontemporal_store(phi, (unsigned int*)(H2 + hrow + u0));
        __builtin_nontemporal_store(plo, (unsigned int*)(H2 + hrow + 512 + u0));
        cstore32(xh2 + b * 2048 + 512 + u0, phi);   // h_hi
        cstore32(xh2 + b * 2048 + 1536 + u0, plo);  // h_lo
      } else {
        h_s[u0] = 0.f; h_s[u0 + 1] = 0.f;
        cstore32(xh2 + b * 2048 + 512 + u0, 0u);
        cstore32(xh2 + b * 2048 + 1536 + u0, 0u);
      }
    }
    if (tau == 50) break;  // finalize-only tail (no barrier after)
    __syncthreads();

    // ---- dec_att (f32 W_dec): dec_s[a] = W_dec[a,:]·h + b_dec[a];  a = tid
    {
      const float4* wr = (const float4*)(Wdec + (size_t)tid * 512);
      float p0 = 0.f, p1 = 0.f, p2 = 0.f, p3 = 0.f;
#pragma unroll 8
      for (int i = 0; i < 128; ++i) {
        float4 w4 = wr[i];
        const float* hh = &h_s[i * 4];
        p0 += w4.x * hh[0];
        p1 += w4.y * hh[1];
        p2 += w4.z * hh[2];
        p3 += w4.w * hh[3];
      }
      dec_s[tid] = (p0 + p1) + (p2 + p3) + b_dec[tid];
      wf_s[tid] = Wfull[tid];
    }
    __syncthreads();

    // ---- scores: s[p] = sum_a wf[a]*relu(encbf[b,p,a]+dec[a]);  p = tid (<196)
    float s = -1e30f;
    if (tid < 196) {
      const unsigned short* er = encbf + (size_t)(b * 196 + tid) * 512;
      float a0 = 0.f, a1 = 0.f, a2 = 0.f, a3 = 0.f;
#pragma unroll 4
      for (int i = 0; i < 64; ++i) {
        short8 e8 = *(const short8*)(er + i * 8);
        a0 += wf_s[i * 8 + 0] * fmaxf(bf2f((unsigned short)e8[0]) + dec_s[i * 8 + 0], 0.f);
        a1 += wf_s[i * 8 + 1] * fmaxf(bf2f((unsigned short)e8[1]) + dec_s[i * 8 + 1], 0.f);
        a2 += wf_s[i * 8 + 2] * fmaxf(bf2f((unsigned short)e8[2]) + dec_s[i * 8 + 2], 0.f);
        a3 += wf_s[i * 8 + 3] * fmaxf(bf2f((unsigned short)e8[3]) + dec_s[i * 8 + 3], 0.f);
        a0 += wf_s[i * 8 + 4] * fmaxf(bf2f((unsigned short)e8[4]) + dec_s[i * 8 + 4], 0.f);
        a1 += wf_s[i * 8 + 5] * fmaxf(bf2f((unsigned short)e8[5]) + dec_s[i * 8 + 5], 0.f);
        a2 += wf_s[i * 8 + 6] * fmaxf(bf2f((unsigned short)e8[6]) + dec_s[i * 8 + 6], 0.f);
        a3 += wf_s[i * 8 + 7] * fmaxf(bf2f((unsigned short)e8[7]) + dec_s[i * 8 + 7], 0.f);
      }
      s = (a0 + a1) + (a2 + a3);
    }
    sm[tid] = s;
    tmp[tid] = s;
    __syncthreads();
    for (int st = 256; st > 0; st >>= 1) {
      if (tid < st) tmp[tid] = fmaxf(tmp[tid], tmp[tid + st]);
      __syncthreads();
    }
    const float mx = tmp[0];
    __syncthreads();
    const float e = (tid < 196) ? expf(sm[tid] - mx) : 0.f;
    tmp[tid] = e;
    __syncthreads();
    for (int st = 256; st > 0; st >>= 1) {
      if (tid < st) tmp[tid] += tmp[tid + st];
      __syncthreads();
    }
    const float inv = 1.f / tmp[0];
    __syncthreads();
    sm[tid] = e * inv;  // alpha
    __syncthreads();

    // ---- awe[e] = sum_p alpha[p]*F2hi[b,p,e];  e = tid
    {
      const unsigned short* fc = F2 + (size_t)(b * 196) * 1024 + tid;
      float a0 = 0.f, a1 = 0.f, a2 = 0.f, a3 = 0.f;
#pragma unroll 4
      for (int p = 0; p < 196; p += 4) {
        a0 += sm[p + 0] * bf2f(fc[(size_t)(p + 0) * 1024]);
        a1 += sm[p + 1] * bf2f(fc[(size_t)(p + 1) * 1024]);
        a2 += sm[p + 2] * bf2f(fc[(size_t)(p + 2) * 1024]);
        a3 += sm[p + 3] * bf2f(fc[(size_t)(p + 3) * 1024]);
      }
      awe_s[tid] = (a0 + a1) + (a2 + a3);
    }
    __syncthreads();
    if (tid < 256) {
      const int e0 = tid << 1;
      float a0 = awe_s[e0], a1 = awe_s[e0 + 1];
      unsigned short a0hi = f2bf(a0), a1hi = f2bf(a1);
      unsigned short a0lo = f2bf(a0 - bf2f(a0hi)), a1lo = f2bf(a1 - bf2f(a1hi));
      cstore32(xh2 + b * 2048 + e0, (unsigned int)a0hi | ((unsigned int)a1hi << 16));
      cstore32(xh2 + b * 2048 + 1024 + e0, (unsigned int)a0lo | ((unsigned int)a1lo << 16));
    }
    gbar32(bar + (size_t)(2 * tau) * BARSTRIDE);

    // ======== phase2: gates GEMM, j-slice jbase=b*64, M=32, full K -> gbuf ========
    {
      const int lane = tid & 63;
      const int w = tid >> 6, mt = w >> 2, nt = w & 3;
      const int jbase = b * 64;
      f32x4 acc = (f32x4){0.f, 0.f, 0.f, 0.f};
      // A-hi stage: xh2 cols [0,1024) (awe_hi|h_hi) -> AS (coherent reads)
#pragma unroll
      for (int it = 0; it < 8; ++it) {
        int idx = it * 512 + tid, r = idx >> 7, c8 = (idx & 127) << 3;
        u64 d0 = cload64(xh2 + (size_t)r * 2048 + c8);
        u64 d1 = cload64(xh2 + (size_t)r * 2048 + c8 + 4);
        short* dst = &AS[r][c8];
        *(u64*)dst = d0;
        *(u64*)(dst + 4) = d1;
      }
      __syncthreads();
      for (int g = 0; g < 6; ++g) {
        if (g == 4) {  // restage A-lo: xh2 cols [1024,2048) (awe_lo|h_lo)
#pragma unroll
          for (int it = 0; it < 8; ++it) {
            int idx = it * 512 + tid, r = idx >> 7, c8 = (idx & 127) << 3;
            u64 d0 = cload64(xh2 + (size_t)r * 2048 + 1024 + c8);
            u64 d1 = cload64(xh2 + (size_t)r * 2048 + 1024 + c8 + 4);
            short* dst = &AS[r][c8];
            *(u64*)dst = d0;
            *(u64*)(dst + 4) = d1;
          }
        }
        // stage 16 k-step B tiles (Wcat2, cached)
#pragma unroll
        for (int it = 0; it < 8; ++it) {
          int ksl = it * 2 + (tid >> 8);
          int ks = g * 16 + ksl;
          int t_ = ks >> 5, k = (ks & 31) << 5;
          int bcol = (t_ == 1) ? 1024 + k : k;
          int rem = tid & 255, rr_ = rem >> 2, cc_ = (rem & 3) << 3;
          gl_lds16(Wcat2 + (size_t)(jbase + rr_) * 2048 + bcol + cc_,
                   BS + ksl * 2048 + rem * 8);
        }
        __syncthreads();
#pragma unroll
        for (int ksl = 0; ksl < 16; ++ksl) {
          int kc = ((g * 16 + ksl) & 31) << 5;
          short8 af = *(const short8*)(&AS[mt * 16 + (lane & 15)][kc + ((lane >> 4) << 3)]);
          short8 bf8 = *(const short8*)(BS + ksl * 2048 + (nt * 16 + (lane & 15)) * 32 +
                                        ((lane >> 4) << 3));
          acc = __builtin_amdgcn_mfma_f32_16x16x32_bf16(af, bf8, acc, 0, 0, 0);
        }
        __syncthreads();
      }
      const int j = jbase + nt * 16 + (lane & 15);
#pragma unroll
      for (int rr = 0; rr < 4; ++rr) {
        const int brow = mt * 16 + (lane >> 4) * 4 + rr;
        cstoref(&gbuf[(size_t)brow * 2048 + j], acc[rr]);
      }
    }
    gbar32(bar + (size_t)(2 * tau + 1) * BARSTRIDE);
  }
}

extern "C" void kernel_launch(void* const* d_in, const int* in_sizes, int n_in,
                              void* d_out, int out_size, void* d_ws, size_t ws_size,
                              hipStream_t stream) {
  const float* features = (const float*)d_in[0];
  const int* captions   = (const int*)d_in[1];
  const float* emb      = (const float*)d_in[2];
  const float* W_ih     = (const float*)d_in[3];
  const float* b_ih     = (const float*)d_in[4];
  const float* W_hh     = (const float*)d_in[5];
  const float* b_hh     = (const float*)d_in[6];
  const float* W_enc    = (const float*)d_in[7];
  const float* b_enc    = (const float*)d_in[8];
  const float* W_dec    = (const float*)d_in[9];
  const float* b_dec    = (const float*)d_in[10];
  const float* W_full   = (const float*)d_in[11];
  // d_in[12] = b_full: constant shift before softmax -> no-op, skipped
  const float* W_out    = (const float*)d_in[13];
  const float* b_out    = (const float*)d_in[14];
  float* out = (float*)d_out;
  (void)in_sizes; (void)n_in; (void)out_size; (void)ws_size;

  char* ws = (char*)d_ws;
  size_t off = 0;
  auto alloc = [&](size_t bytes) -> void* {
    void* p = ws + off;
    off = (off + bytes + 255) & ~(size_t)255;
    return p;
  };
  unsigned short* encbf = (unsigned short*)alloc(6272ull * 512 * 2);
  unsigned short* F2    = (unsigned short*)alloc(6272ull * 1024 * 2);
  unsigned short* We2   = (unsigned short*)alloc(512ull * 1024 * 2);
  unsigned short* X2    = (unsigned short*)alloc(1600ull * 1024 * 2);
  unsigned short* WihX2 = (unsigned short*)alloc(2048ull * 1024 * 2);
  unsigned short* Wout2 = (unsigned short*)alloc(32000ull * 1024 * 2);
  unsigned short* H2    = (unsigned short*)alloc(1600ull * 1024 * 2);
  float* gates_x        = (float*)alloc(1600ull * 2048 * 4);
  unsigned short* Wcat2 = (unsigned short*)alloc(2048ull * 2048 * 2);
  unsigned short* xh2   = (unsigned short*)alloc(32ull * 2048 * 2);
  float* gbuf           = (float*)alloc(32ull * 2048 * 4);
  unsigned int* bar     = (unsigned int*)alloc((size_t)NBAR * BARSTRIDE * 4);

  // ---- prep (hoisted, data-parallel)
  k_zero<<<(NBAR * BARSTRIDE + 255) / 256, 256, 0, stream>>>(bar, NBAR * BARSTRIDE);
  k_split<<<2048, 256, 0, stream>>>(features, F2, 6272, 512);
  k_split<<<512, 256, 0, stream>>>(W_enc, We2, 512, 512);
  k_split<<<2048, 256, 0, stream>>>(W_ih, WihX2, 2048, 1024);   // x_t half of W_ih
  k_split<<<2048, 256, 0, stream>>>(W_out, Wout2, 32000, 512);
  k_wcat2<<<2048, 256, 0, stream>>>(W_ih, W_hh, Wcat2);
  k_xgather<<<2048, 256, 0, stream>>>(captions, emb, X2);

  // ---- hoisted GEMMs
  // enc_att = features @ W_enc^T + b_enc  -> bf16 directly   [6272, 512]
  k_gemm<<<dim3(4, 49), 256, 0, stream>>>(F2, We2, nullptr, encbf, b_enc, nullptr, 6272, 512);
  // gates_x = emb(captions) @ W_ih[:, :512]^T + b_ih + b_hh   [1600, 2048]
  k_gemm<<<dim3(16, 13), 256, 0, stream>>>(X2, WihX2, gates_x, nullptr, b_ih, b_hh, 1600, 2048);

  // ---- sequential scan: one 32-block persistent kernel, 2 cheap barriers/step
  k_scan32<<<32, 512, 0, stream>>>(gates_x, H2, xh2, W_dec, b_dec, encbf, W_full,
                                   F2, Wcat2, gbuf, bar);

  // ---- final: out[b,t,:] = h_{t+1}[b] @ W_out^T + b_out  (rows already b*50+t)
  k_gemm<<<dim3(250, 13), 256, 0, stream>>>(H2, Wout2, out, nullptr, b_out, nullptr, 1600, 32000);
}

// Round 8
// 1914.503 us; speedup vs baseline: 2.1150x; 2.1150x over previous
//
#include <hip/hip_runtime.h>
#include <hip/hip_bf16.h>

// DecoderRNN: B=32,P=196,E=H=A=512,V=32000,T=50
// v9: 2-launch scan via the WF factorization.
//   gates_awe[b,j] = sum_p alpha[b,p] * WF[b,p,j],  WF = features @ W_ih_awe^T
//   (hoisted GEMM, bf16, 25.7MB, L3-resident)  ->  awe never materializes; the
//   only per-step cross-batch stage left is the h-GEMM (MFMA).
//   A = round-0 k_p1 (finalize + dec_att slice + partial scores), proven 6us.
//   B = dual-role: softmax+gates_awe (per-batch j-slice) AND h-GEMM k-slice
//       (MFMA, stages issued first to hide latency under softmax VALU).
//   All sync via graph-replayed launches (6us) — no software barriers (r2-r7).

typedef __attribute__((ext_vector_type(8))) short short8;
typedef __attribute__((ext_vector_type(4))) float f32x4;

__device__ __forceinline__ unsigned short f2bf(float x) {
  __hip_bfloat16 h = __float2bfloat16(x);
  return __builtin_bit_cast(unsigned short, h);
}
__device__ __forceinline__ float bf2f(unsigned short u) {
  unsigned int v = ((unsigned int)u) << 16;
  return __builtin_bit_cast(float, v);
}
__device__ __forceinline__ void gl_lds16(const void* g, void* l) {
  __builtin_amdgcn_global_load_lds(
      (const __attribute__((address_space(1))) unsigned int*)g,
      (__attribute__((address_space(3))) unsigned int*)l, 16, 0, 0);
}

// ---- prep: f32 [rows,512] -> bf16 split [rows,1024] ([0,512)=hi, [512,1024)=lo)
__global__ void k_split(const float* __restrict__ src, unsigned short* __restrict__ dst,
                        int rows, int src_ld) {
  int n = rows * 512;
  for (int i = blockIdx.x * blockDim.x + threadIdx.x; i < n; i += gridDim.x * blockDim.x) {
    int r = i >> 9, c = i & 511;
    float x = src[(size_t)r * src_ld + c];
    unsigned short hi = f2bf(x);
    unsigned short lo = f2bf(x - bf2f(hi));
    dst[(size_t)r * 1024 + c] = hi;
    dst[(size_t)r * 1024 + 512 + c] = lo;
  }
}

// ---- prep: plain f32 -> bf16
__global__ void k_bf16c(const float* __restrict__ src, unsigned short* __restrict__ dst, int n) {
  for (int i = blockIdx.x * blockDim.x + threadIdx.x; i < n; i += gridDim.x * blockDim.x)
    dst[i] = f2bf(src[i]);
}

// ---- prep: X2 [1600,1024] split-bf16 of emb[captions]; row m = b*50+t
__global__ void k_xgather(const int* __restrict__ captions, const float* __restrict__ emb,
                          unsigned short* __restrict__ X2) {
  int n = 1600 * 512;
  for (int i = blockIdx.x * blockDim.x + threadIdx.x; i < n; i += gridDim.x * blockDim.x) {
    int m = i >> 9, c = i & 511;
    int tok = captions[m];
    float x = emb[(size_t)tok * 512 + c];
    unsigned short hi = f2bf(x);
    unsigned short lo = f2bf(x - bf2f(hi));
    X2[(size_t)m * 1024 + c] = hi;
    X2[(size_t)m * 1024 + 512 + c] = lo;
  }
}

// ---- split-bf16 GEMM: C[m,n] = sum_k A[m,:]·B[n,:] (3-term hi/lo) + bias1[n] + bias2[n]
// A2 [M,1024], B2 [N,1024]. 128x128 tile, m97 pattern.  Output f32 (C) or bf16 (C16).
// Bijective XCD-chunked swizzle, M-fastest decode.
__global__ void k_gemm(const unsigned short* __restrict__ A2, const unsigned short* __restrict__ B2,
                       float* __restrict__ C, unsigned short* __restrict__ C16,
                       const float* __restrict__ bias1, const float* __restrict__ bias2,
                       int M, int N) {
  __shared__ short As[128 * 32];
  __shared__ short Bs[128 * 32];
  const int tid = threadIdx.x;
  const int lane = tid & 63;
  const int w = tid >> 6, wm = w >> 1, wn = w & 1;

  const int nbx = gridDim.x, nby = gridDim.y;
  const int nwg = nbx * nby;
  const int bidl = blockIdx.y * nbx + blockIdx.x;
  int flat = bidl;
  if (nwg >= 16) {  // bijective chunked XCD swizzle (m204 formula)
    const int q = nwg >> 3, rrem = nwg & 7;
    const int xcd = bidl & 7, idx = bidl >> 3;
    flat = (xcd < rrem) ? xcd * (q + 1) + idx : rrem * (q + 1) + (xcd - rrem) * q + idx;
  }
  const int mb = flat % nby, nb = flat / nby;  // M fastest: same-N tiles contiguous
  const int m0 = mb * 128, n0 = nb * 128;

  f32x4 acc[4][4];
#pragma unroll
  for (int i = 0; i < 4; ++i)
#pragma unroll
    for (int j = 0; j < 4; ++j) acc[i][j] = (f32x4){0.f, 0.f, 0.f, 0.f};

  const int r0 = tid >> 2;
  const int ce = (tid & 3) << 3;
  int am0 = m0 + r0;      if (am0 >= M) am0 = 0;
  int am1 = m0 + 64 + r0; if (am1 >= M) am1 = 0;
  const int bn0 = n0 + r0, bn1 = n0 + 64 + r0;

  for (int ks = 0; ks < 48; ++ks) {
    int t_ = ks >> 4, k = (ks & 15) << 5;
    int acol = (t_ == 2) ? 512 + k : k;
    int bcol = (t_ == 1) ? 512 + k : k;
    __syncthreads();
    gl_lds16(A2 + (size_t)am0 * 1024 + acol + ce, As + tid * 8);
    gl_lds16(A2 + (size_t)am1 * 1024 + acol + ce, As + 2048 + tid * 8);
    gl_lds16(B2 + (size_t)bn0 * 1024 + bcol + ce, Bs + tid * 8);
    gl_lds16(B2 + (size_t)bn1 * 1024 + bcol + ce, Bs + 2048 + tid * 8);
    __syncthreads();
    short8 af[4], bf[4];
#pragma unroll
    for (int mi = 0; mi < 4; ++mi) {
      int row = wm * 64 + mi * 16 + (lane & 15);
      af[mi] = *(const short8*)(As + row * 32 + (lane >> 4) * 8);
    }
#pragma unroll
    for (int ni = 0; ni < 4; ++ni) {
      int row = wn * 64 + ni * 16 + (lane & 15);
      bf[ni] = *(const short8*)(Bs + row * 32 + (lane >> 4) * 8);
    }
#pragma unroll
    for (int mi = 0; mi < 4; ++mi)
#pragma unroll
      for (int ni = 0; ni < 4; ++ni)
        acc[mi][ni] = __builtin_amdgcn_mfma_f32_16x16x32_bf16(af[mi], bf[ni], acc[mi][ni], 0, 0, 0);
  }

  const int mbb = m0 + wm * 64, nbb = n0 + wn * 64;
#pragma unroll
  for (int ni = 0; ni < 4; ++ni) {
    int n = nbb + ni * 16 + (lane & 15);
    float bv = 0.f;
    if (bias1) bv += bias1[n];
    if (bias2) bv += bias2[n];
#pragma unroll
    for (int mi = 0; mi < 4; ++mi)
#pragma unroll
      for (int r = 0; r < 4; ++r) {
        int m = mbb + mi * 16 + (lane >> 4) * 4 + r;
        if (m < M) {
          float v = acc[mi][ni][r] + bv;
          if (C16) C16[(size_t)m * N + n] = f2bf(v);
          else C[(size_t)m * N + n] = v;
        }
      }
  }
}

// ---- A (per step): finalize gates(tau-1) = gates_x + gawe + sum_8 gph -> LSTM -> h;
//      dec_att a-slice + partial scores over a-slice -> spart.  grid 256 = (b, ablk).
//      cbuf replicated per ablk (no cross-block race).  Round-0 k_p1 structure.
__global__ void k_pA(int tau, const float* __restrict__ gph, const float* __restrict__ gawe,
                     const float* __restrict__ gates_x, float* __restrict__ cbuf,
                     unsigned short* __restrict__ H2, unsigned short* __restrict__ xcur,
                     const unsigned short* __restrict__ Wdec2, const float* __restrict__ b_dec,
                     const unsigned short* __restrict__ encbf, const float* __restrict__ Wfull,
                     float* __restrict__ spart) {
  const int b = blockIdx.x >> 3, ablk = blockIdx.x & 7;
  const int tid = threadIdx.x;
  __shared__ float h_s[512];
  __shared__ float red[64][4];
  __shared__ float dec_s[64];
  __shared__ float wf_s[64];

  float* cb = cbuf + ((size_t)ablk * 32 + b) * 512;  // private replica
  if (tau > 0) {
    const float* gx = gates_x + (size_t)(b * 50 + (tau - 1)) * 2048;
    const float* ga = gawe + (size_t)b * 2048;
    for (int u = tid; u < 512; u += 256) {
      float gi = gx[u] + ga[u];
      float gf = gx[512 + u] + ga[512 + u];
      float gg = gx[1024 + u] + ga[1024 + u];
      float go = gx[1536 + u] + ga[1536 + u];
#pragma unroll
      for (int kp = 0; kp < 8; ++kp) {
        const float* gp = gph + (size_t)(kp * 32 + b) * 2048;
        gi += gp[u]; gf += gp[512 + u]; gg += gp[1024 + u]; go += gp[1536 + u];
      }
      float c_old = cb[u];
      float si = 1.f / (1.f + expf(-gi));
      float sf = 1.f / (1.f + expf(-gf));
      float so = 1.f / (1.f + expf(-go));
      float cn = sf * c_old + si * tanhf(gg);
      float hn = so * tanhf(cn);
      cb[u] = cn;
      h_s[u] = hn;
      unsigned short hi = f2bf(hn), lo = f2bf(hn - bf2f(hi));
      size_t hrow = (size_t)(b * 50 + (tau - 1)) * 1024;
      H2[hrow + u] = hi; H2[hrow + 512 + u] = lo;  // dup writes across ablk: benign
      xcur[b * 1024 + u] = hi;
      xcur[b * 1024 + 512 + u] = lo;
    }
  } else {
    for (int u = tid; u < 512; u += 256) {
      h_s[u] = 0.f;
      cb[u] = 0.f;  // re-init every call (graph replay safe)
      xcur[b * 1024 + u] = 0;
      xcur[b * 1024 + 512 + u] = 0;
    }
  }
  if (tau >= 50) return;  // finalize-only launch
  __syncthreads();

  // dec_att for a-slice [ablk*64, +64): 4 threads per a, 128-u partials each
  const int abase = ablk * 64;
  const int al = tid >> 2, q = tid & 3;
  {
    const unsigned short* wr = Wdec2 + (size_t)(abase + al) * 512 + q * 128;
    float p = 0.f;
#pragma unroll
    for (int i = 0; i < 16; ++i) {
      short8 w8 = *(const short8*)(wr + i * 8);
      const float* hh = &h_s[q * 128 + i * 8];
#pragma unroll
      for (int e = 0; e < 8; ++e) p += bf2f((unsigned short)w8[e]) * hh[e];
    }
    red[al][q] = p;
  }
  __syncthreads();
  if (tid < 64) {
    dec_s[tid] = red[tid][0] + red[tid][1] + red[tid][2] + red[tid][3] + b_dec[abase + tid];
    wf_s[tid] = Wfull[abase + tid];
  }
  __syncthreads();

  // partial scores: s_part[b,p,ablk] = sum_{a in slice} Wfull[a]*relu(enc+dec)  (bf16 enc)
  if (tid < 196) {
    const unsigned short* er = encbf + (size_t)(b * 196 + tid) * 512 + abase;
    float s = 0.f;
#pragma unroll
    for (int i = 0; i < 8; ++i) {
      short8 e8 = *(const short8*)(er + i * 8);
#pragma unroll
      for (int a = 0; a < 8; ++a)
        s += wf_s[i * 8 + a] * fmaxf(bf2f((unsigned short)e8[a]) + dec_s[i * 8 + a], 0.f);
    }
    spart[(b * 196 + tid) * 8 + ablk] = s;
  }
}

// ---- B (per step), dual-role, grid 256 = (g1, g2):
//  role i  (jtile=g1, kblk=g2): h-GEMM k-slice: gph[kblk][b][jslice] via 8 MFMAs
//          over xcur (h hi|lo) x Whh2; stages issued FIRST (latency hidden by softmax).
//  role ii (b=g1, jblk=g2): softmax(spart) -> alpha; gates_awe[b, jblk*256..+256)
//          = sum_p alpha[p]*WF[b,p,j]  (bf16 WF, coalesced column reads).
__global__ void k_pB(const unsigned short* __restrict__ xcur, const unsigned short* __restrict__ Whh2,
                     const float* __restrict__ spart, const unsigned short* __restrict__ WFbf,
                     float* __restrict__ gph, float* __restrict__ gawe) {
  __shared__ short As4[4 * 32 * 32];   // 8 KB
  __shared__ short Bs4[4 * 64 * 32];   // 16 KB
  __shared__ float sm[256], tmp[256];
  const int tid = threadIdx.x;
  const int lane = tid & 63;
  const int w = tid >> 6;
  const int g1 = blockIdx.x >> 3, g2 = blockIdx.x & 7;

  // ---- role i stage: issue all 4 k-step tiles (async DMA)
  {
    const int r = tid >> 2, ce = (tid & 3) << 3;
#pragma unroll
    for (int s = 0; s < 4; ++s) {
      int ks = g2 * 4 + s;              // 32 k-steps: hi 0-15, lo 16-31
      int t_ = ks >> 4, k = (ks & 15) << 5;
      int col = t_ * 512 + k;           // same layout for xcur and Whh2 (hi|lo)
      if (tid < 128) gl_lds16(xcur + (size_t)r * 1024 + col + ce, As4 + s * 1024 + tid * 8);
      gl_lds16(Whh2 + (size_t)(g1 * 64 + r) * 1024 + col + ce, Bs4 + s * 2048 + tid * 8);
    }
  }

  // ---- role ii: softmax for batch g1 (VALU work overlaps the DMA above)
  float s_ = -1e30f;
  if (tid < 196) {
    const float* sp = spart + (size_t)(g1 * 196 + tid) * 8;
    s_ = ((sp[0] + sp[1]) + (sp[2] + sp[3])) + ((sp[4] + sp[5]) + (sp[6] + sp[7]));
  }
  sm[tid] = s_;
  tmp[tid] = s_;
  __syncthreads();
  for (int st = 128; st > 0; st >>= 1) {
    if (tid < st) tmp[tid] = fmaxf(tmp[tid], tmp[tid + st]);
    __syncthreads();
  }
  const float mx = tmp[0];
  __syncthreads();
  const float e = (tid < 196) ? expf(sm[tid] - mx) : 0.f;
  tmp[tid] = e;
  __syncthreads();
  for (int st = 128; st > 0; st >>= 1) {
    if (tid < st) tmp[tid] += tmp[tid + st];
    __syncthreads();
  }
  const float inv = 1.f / tmp[0];
  __syncthreads();
  sm[tid] = e * inv;  // alpha
  __syncthreads();

  // ---- role i MFMAs (stages drained by softmax's syncthreads)
  {
    f32x4 acc0 = (f32x4){0.f, 0.f, 0.f, 0.f}, acc1 = (f32x4){0.f, 0.f, 0.f, 0.f};
#pragma unroll
    for (int s = 0; s < 4; ++s) {
      short8 a0f = *(const short8*)(As4 + s * 1024 + (lane & 15) * 32 + (lane >> 4) * 8);
      short8 a1f = *(const short8*)(As4 + s * 1024 + (16 + (lane & 15)) * 32 + (lane >> 4) * 8);
      short8 bbf = *(const short8*)(Bs4 + s * 2048 + (w * 16 + (lane & 15)) * 32 + (lane >> 4) * 8);
      acc0 = __builtin_amdgcn_mfma_f32_16x16x32_bf16(a0f, bbf, acc0, 0, 0, 0);
      acc1 = __builtin_amdgcn_mfma_f32_16x16x32_bf16(a1f, bbf, acc1, 0, 0, 0);
    }
    const int j = g1 * 64 + w * 16 + (lane & 15);
#pragma unroll
    for (int rr = 0; rr < 4; ++rr) {
      const int brow = (lane >> 4) * 4 + rr;
      gph[(size_t)(g2 * 32 + brow) * 2048 + j] = acc0[rr];
      gph[(size_t)(g2 * 32 + 16 + brow) * 2048 + j] = acc1[rr];
    }
  }

  // ---- role ii: gates_awe j-slice, 196 MACs/thread (coalesced WF columns)
  {
    const int j = g2 * 256 + tid;
    const unsigned short* wc = WFbf + (size_t)(g1 * 196) * 2048 + j;
    float a0 = 0.f, a1 = 0.f, a2 = 0.f, a3 = 0.f;
#pragma unroll 4
    for (int p = 0; p < 196; p += 4) {
      a0 += sm[p + 0] * bf2f(wc[(size_t)(p + 0) * 2048]);
      a1 += sm[p + 1] * bf2f(wc[(size_t)(p + 1) * 2048]);
      a2 += sm[p + 2] * bf2f(wc[(size_t)(p + 2) * 2048]);
      a3 += sm[p + 3] * bf2f(wc[(size_t)(p + 3) * 2048]);
    }
    gawe[(size_t)g1 * 2048 + j] = (a0 + a1) + (a2 + a3);
  }
}

extern "C" void kernel_launch(void* const* d_in, const int* in_sizes, int n_in,
                              void* d_out, int out_size, void* d_ws, size_t ws_size,
                              hipStream_t stream) {
  const float* features = (const float*)d_in[0];
  const int* captions   = (const int*)d_in[1];
  const float* emb      = (const float*)d_in[2];
  const float* W_ih     = (const float*)d_in[3];
  const float* b_ih     = (const float*)d_in[4];
  const float* W_hh     = (const float*)d_in[5];
  const float* b_hh     = (const float*)d_in[6];
  const float* W_enc    = (const float*)d_in[7];
  const float* b_enc    = (const float*)d_in[8];
  const float* W_dec    = (const float*)d_in[9];
  const float* b_dec    = (const float*)d_in[10];
  const float* W_full   = (const float*)d_in[11];
  // d_in[12] = b_full: constant shift before softmax -> no-op, skipped
  const float* W_out    = (const float*)d_in[13];
  const float* b_out    = (const float*)d_in[14];
  float* out = (float*)d_out;
  (void)in_sizes; (void)n_in; (void)out_size; (void)ws_size;

  char* ws = (char*)d_ws;
  size_t off = 0;
  auto alloc = [&](size_t bytes) -> void* {
    void* p = ws + off;
    off = (off + bytes + 255) & ~(size_t)255;
    return p;
  };
  unsigned short* encbf = (unsigned short*)alloc(6272ull * 512 * 2);
  unsigned short* F2    = (unsigned short*)alloc(6272ull * 1024 * 2);
  unsigned short* We2   = (unsigned short*)alloc(512ull * 1024 * 2);
  unsigned short* X2    = (unsigned short*)alloc(1600ull * 1024 * 2);
  unsigned short* WihX2 = (unsigned short*)alloc(2048ull * 1024 * 2);
  unsigned short* Wawe2 = (unsigned short*)alloc(2048ull * 1024 * 2);
  unsigned short* Whh2  = (unsigned short*)alloc(2048ull * 1024 * 2);
  unsigned short* Wout2 = (unsigned short*)alloc(32000ull * 1024 * 2);
  unsigned short* WFbf  = (unsigned short*)alloc(6272ull * 2048 * 2);
  unsigned short* H2    = (unsigned short*)alloc(1600ull * 1024 * 2);
  float* gates_x        = (float*)alloc(1600ull * 2048 * 4);
  unsigned short* Wdec2 = (unsigned short*)alloc(512ull * 512 * 2);
  unsigned short* xcur  = (unsigned short*)alloc(32ull * 1024 * 2);
  float* spart          = (float*)alloc(32ull * 196 * 8 * 4);
  float* gph            = (float*)alloc(8ull * 32 * 2048 * 4);
  float* gawe           = (float*)alloc(32ull * 2048 * 4);
  float* cbuf           = (float*)alloc(8ull * 32 * 512 * 4);

  // ---- prep (hoisted, data-parallel)
  k_split<<<2048, 256, 0, stream>>>(features, F2, 6272, 512);
  k_split<<<512, 256, 0, stream>>>(W_enc, We2, 512, 512);
  k_split<<<2048, 256, 0, stream>>>(W_ih, WihX2, 2048, 1024);        // x_t half
  k_split<<<2048, 256, 0, stream>>>(W_ih + 512, Wawe2, 2048, 1024);  // awe half
  k_split<<<2048, 256, 0, stream>>>(W_hh, Whh2, 2048, 512);
  k_split<<<2048, 256, 0, stream>>>(W_out, Wout2, 32000, 512);
  k_bf16c<<<512, 256, 0, stream>>>(W_dec, Wdec2, 512 * 512);
  k_xgather<<<2048, 256, 0, stream>>>(captions, emb, X2);

  // ---- hoisted GEMMs
  // enc_att -> bf16 directly   [6272, 512]
  k_gemm<<<dim3(4, 49), 256, 0, stream>>>(F2, We2, nullptr, encbf, b_enc, nullptr, 6272, 512);
  // gates_x = emb(captions) @ W_ih[:, :512]^T + b_ih + b_hh   [1600, 2048]
  k_gemm<<<dim3(16, 13), 256, 0, stream>>>(X2, WihX2, gates_x, nullptr, b_ih, b_hh, 1600, 2048);
  // WF = features @ W_ih_awe^T -> bf16   [6272, 2048]
  k_gemm<<<dim3(16, 49), 256, 0, stream>>>(F2, Wawe2, nullptr, WFbf, nullptr, nullptr, 6272, 2048);

  // ---- sequential scan: 2 launches per step
  for (int tau = 0; tau <= 50; ++tau) {
    k_pA<<<256, 256, 0, stream>>>(tau, gph, gawe, gates_x, cbuf, H2, xcur, Wdec2,
                                  b_dec, encbf, W_full, spart);
    if (tau < 50)
      k_pB<<<256, 256, 0, stream>>>(xcur, Whh2, spart, WFbf, gph, gawe);
  }

  // ---- final: out[b,t,:] = h_{t+1}[b] @ W_out^T + b_out  (rows already b*50+t)
  k_gemm<<<dim3(250, 13), 256, 0, stream>>>(H2, Wout2, out, nullptr, b_out, nullptr, 1600, 32000);
}